// Round 7
// baseline (352.396 us; speedup 1.0000x reference)
//
#include <hip/hip_runtime.h>

#define NN 50000
#define NE 800000
#define NB 196          // (NN+255)/256
#define GB1 391         // (NN+127)/128 gemm blocks in fused kernel
#define HB1 3125        // NE/256 hist blocks
#define BN_EPS 1e-5f

typedef __attribute__((ext_vector_type(8))) short short8;
typedef __attribute__((ext_vector_type(16))) float f32x16;

static __device__ __forceinline__ unsigned short f2bf(float f) {
    union { float f; unsigned u; } v; v.f = f;
    unsigned r = (v.u + 0x7FFF + ((v.u >> 16) & 1)) >> 16;
    return (unsigned short)r;
}
static __device__ __forceinline__ float bf2f(unsigned short s) {
    union { unsigned u; float f; } v; v.u = ((unsigned)s) << 16;
    return v.f;
}

// ---------------- fused: layer-1 GEMM (blocks [0,GB1)) + degree/rank hist ----------------
__global__ __launch_bounds__(256) void k_gemm1_deg(
    const float* __restrict__ X, const float* __restrict__ W,
    unsigned short* __restrict__ Y,
    const int* __restrict__ dst, int* __restrict__ deg, int* __restrict__ rank) {
    __shared__ unsigned short Wt[128 * 136];  // [n][k]
    int t = threadIdx.x;

    if (blockIdx.x >= GB1) {
        int e = (blockIdx.x - GB1) * 256 + t;
        if (e < NE) rank[e] = atomicAdd(&deg[dst[e]], 1);
        return;
    }

    for (int i = t; i < 16384; i += 256) {
        int k = i >> 7, n = i & 127;
        Wt[n * 136 + k] = f2bf(W[i]);
    }
    __syncthreads();

    int wv = t >> 6;
    int l = t & 63;
    int l31 = l & 31;
    int khalf = l >> 5;
    int rowb = blockIdx.x * 128 + wv * 32;
    int myrow = rowb + l31;
    int rowc = myrow < NN ? myrow : NN - 1;

    f32x16 acc[4];
#pragma unroll
    for (int nt = 0; nt < 4; ++nt)
#pragma unroll
        for (int r = 0; r < 16; ++r) acc[nt][r] = 0.f;

#pragma unroll
    for (int ks = 0; ks < 8; ++ks) {
        int kk = ks * 16;
        const float* ap = X + (size_t)rowc * 128 + kk + khalf * 8;
        float4 f0 = ((const float4*)ap)[0];
        float4 f1 = ((const float4*)ap)[1];
        short8 a;
        a[0] = (short)f2bf(f0.x); a[1] = (short)f2bf(f0.y);
        a[2] = (short)f2bf(f0.z); a[3] = (short)f2bf(f0.w);
        a[4] = (short)f2bf(f1.x); a[5] = (short)f2bf(f1.y);
        a[6] = (short)f2bf(f1.z); a[7] = (short)f2bf(f1.w);
#pragma unroll
        for (int nt = 0; nt < 4; ++nt) {
            short8 b = *(const short8*)&Wt[(nt * 32 + l31) * 136 + kk + khalf * 8];
            acc[nt] = __builtin_amdgcn_mfma_f32_32x32x16_bf16(a, b, acc[nt], 0, 0, 0);
        }
    }

#pragma unroll
    for (int r = 0; r < 16; ++r) {
        int m = (r & 3) + 8 * (r >> 2) + 4 * khalf;
        int grow = rowb + m;
        if (grow < NN) {
#pragma unroll
            for (int nt = 0; nt < 4; ++nt)
                Y[(size_t)grow * 128 + nt * 32 + l31] = f2bf(acc[nt][r]);
        }
    }
}

// ---------------- hierarchical scan (196 blocks), dinv fused; rp stays PARTIAL ----------------
__global__ __launch_bounds__(256) void k_scan1(const int* __restrict__ deg,
                                               int* __restrict__ rp,
                                               int* __restrict__ bsum,
                                               float* __restrict__ dinv) {
    __shared__ int s[256];
    int t = threadIdx.x;
    int i = blockIdx.x * 256 + t;
    int v = (i < NN) ? deg[i] : 0;
    if (i < NN) dinv[i] = rsqrtf((float)(v + 1));  // +1 self-loop
    s[t] = v;
    __syncthreads();
    for (int off = 1; off < 256; off <<= 1) {
        int add = (t >= off) ? s[t - off] : 0;
        __syncthreads();
        s[t] += add;
        __syncthreads();
    }
    if (i < NN) rp[i] = s[t] - v;
    if (t == 255) bsum[blockIdx.x] = s[255];
}

__global__ __launch_bounds__(256) void k_scan2_bn(
    int* __restrict__ bsum,
    const float* b1, const float* g1, const float* be1, const float* m1, const float* v1,
    const float* b2, const float* g2, const float* be2, const float* m2, const float* v2,
    float* sc1, float* sh1, float* sc2, float* sh2) {
    __shared__ int s[256];
    int t = threadIdx.x;
    int v = (t < NB) ? bsum[t] : 0;
    s[t] = v;
    __syncthreads();
    for (int off = 1; off < 256; off <<= 1) {
        int add = (t >= off) ? s[t - off] : 0;
        __syncthreads();
        s[t] += add;
        __syncthreads();
    }
    if (t < NB) bsum[t] = s[t] - v;
    if (t < 128) {
        float s1 = rsqrtf(v1[t] + BN_EPS) * g1[t];
        sc1[t] = s1; sh1[t] = be1[t] + (b1[t] - m1[t]) * s1;
        float s2 = rsqrtf(v2[t] + BN_EPS) * g2[t];
        sc2[t] = s2; sh2[t] = be2[t] + (b2[t] - m2[t]) * s2;
    }
}

// row start from partial prefix + block offsets
static __device__ __forceinline__ int rowstart(const int* __restrict__ rp,
                                               const int* __restrict__ bsum, int i) {
    return rp[i] + bsum[i >> 8];
}

// ---------------- CSR fill: no atomics, no scan3 ----------------
__global__ void k_fill(const int* __restrict__ src, const int* __restrict__ dst,
                       const int* __restrict__ rp, const int* __restrict__ bsum,
                       const int* __restrict__ rank, int* __restrict__ eidx) {
    int e = blockIdx.x * blockDim.x + threadIdx.x;
    if (e >= NE) return;
    int d = dst[e];
    eidx[rowstart(rp, bsum, d) + rank[e]] = src[e];
}

// ---------------- MFMA GEMM 128->128 (unscaled) ----------------
__global__ __launch_bounds__(256) void k_mfma_gemm128(
    const unsigned short* __restrict__ Xb, const float* __restrict__ W,
    unsigned short* __restrict__ Y) {
    __shared__ unsigned short Wt[128 * 136];
    int t = threadIdx.x;
    for (int i = t; i < 16384; i += 256) {
        int k = i >> 7, n = i & 127;
        Wt[n * 136 + k] = f2bf(W[i]);
    }
    __syncthreads();

    int wv = t >> 6;
    int l = t & 63;
    int l31 = l & 31;
    int khalf = l >> 5;
    int rowb = blockIdx.x * 128 + wv * 32;
    int myrow = rowb + l31;
    int rowc = myrow < NN ? myrow : NN - 1;

    f32x16 acc[4];
#pragma unroll
    for (int nt = 0; nt < 4; ++nt)
#pragma unroll
        for (int r = 0; r < 16; ++r) acc[nt][r] = 0.f;

#pragma unroll
    for (int ks = 0; ks < 8; ++ks) {
        int kk = ks * 16;
        short8 a = *(const short8*)(Xb + (size_t)rowc * 128 + kk + khalf * 8);
#pragma unroll
        for (int nt = 0; nt < 4; ++nt) {
            short8 b = *(const short8*)&Wt[(nt * 32 + l31) * 136 + kk + khalf * 8];
            acc[nt] = __builtin_amdgcn_mfma_f32_32x32x16_bf16(a, b, acc[nt], 0, 0, 0);
        }
    }

#pragma unroll
    for (int r = 0; r < 16; ++r) {
        int m = (r & 3) + 8 * (r >> 2) + 4 * khalf;
        int grow = rowb + m;
        if (grow < NN) {
#pragma unroll
            for (int nt = 0; nt < 4; ++nt)
                Y[(size_t)grow * 128 + nt * 32 + l31] = f2bf(acc[nt][r]);
        }
    }
}

// ---------------- agg layer-1: 1 node/wave, 8 slots x 8 ch-lanes, bn+relu -> bf16 ----------------
__global__ __launch_bounds__(256) void k_agg128_bnrelu(
    const unsigned short* __restrict__ Ts, const int* __restrict__ rp,
    const int* __restrict__ bsum, const int* __restrict__ eidx,
    const float* __restrict__ dinv,
    const float* __restrict__ sc, const float* __restrict__ sh,
    unsigned short* __restrict__ Z) {
    int node = blockIdx.x * 4 + (threadIdx.x >> 6);
    int l = threadIdx.x & 63;
    int grp = l >> 3;       // edge slot 0..7
    int cl = l & 7;         // channel chunk (16 ch)
    const float4* Tv = (const float4*)Ts;
    float di = dinv[node];

    float acc[16];
    if (grp == 0) {
        float4 a0 = Tv[(size_t)node * 16 + cl * 2 + 0];
        float4 a1 = Tv[(size_t)node * 16 + cl * 2 + 1];
        const unsigned short* u0 = (const unsigned short*)&a0;
        const unsigned short* u1 = (const unsigned short*)&a1;
#pragma unroll
        for (int j = 0; j < 8; ++j) {
            acc[j] = di * bf2f(u0[j]);
            acc[8 + j] = di * bf2f(u1[j]);
        }
    } else {
#pragma unroll
        for (int j = 0; j < 16; ++j) acc[j] = 0.f;
    }

    int e0 = rowstart(rp, bsum, node);
    int e1 = (node + 1 < NN) ? rowstart(rp, bsum, node + 1) : NE;
    for (int e = e0 + grp; e < e1; e += 8) {
        int s = eidx[e];
        float ds = dinv[s];
        float4 g0 = Tv[(size_t)s * 16 + cl * 2 + 0];
        float4 g1 = Tv[(size_t)s * 16 + cl * 2 + 1];
        const unsigned short* u0 = (const unsigned short*)&g0;
        const unsigned short* u1 = (const unsigned short*)&g1;
#pragma unroll
        for (int j = 0; j < 8; ++j) {
            acc[j] += ds * bf2f(u0[j]);
            acc[8 + j] += ds * bf2f(u1[j]);
        }
    }

    // butterfly: all lanes end with full sums
#pragma unroll
    for (int j = 0; j < 16; ++j) {
        acc[j] += __shfl_xor(acc[j], 8);
        acc[j] += __shfl_xor(acc[j], 16);
        acc[j] += __shfl_xor(acc[j], 32);
    }

    if (grp < 2) {  // 16 writer lanes, one float4 (8 ch) each
        int h = grp;  // which half of the 16-ch chunk
        float4 o;
        unsigned short* ov = (unsigned short*)&o;
#pragma unroll
        for (int j = 0; j < 8; ++j) {
            int ch = cl * 16 + h * 8 + j;
            float scv = sc[ch], shv = sh[ch];
            ov[j] = f2bf(fmaxf(acc[h * 8 + j] * di * scv + shv, 0.f));
        }
        ((float4*)Z)[(size_t)node * 16 + cl * 2 + h] = o;
    }
}

// ---------------- agg layer-2 + fused z@W3: writes Tc (bf16, 16 ch) directly ----------------
__global__ __launch_bounds__(256) void k_agg128_bnrelu_g16(
    const unsigned short* __restrict__ Ts, const int* __restrict__ rp,
    const int* __restrict__ bsum, const int* __restrict__ eidx,
    const float* __restrict__ dinv,
    const float* __restrict__ sc, const float* __restrict__ sh,
    const float* __restrict__ W3, unsigned short* __restrict__ Tc) {
    int node = blockIdx.x * 4 + (threadIdx.x >> 6);
    int l = threadIdx.x & 63;
    int grp = l >> 3;       // edge slot 0..7
    int cl = l & 7;         // channel chunk (16 ch)
    const float4* Tv = (const float4*)Ts;
    float di = dinv[node];

    float acc[16];
    if (grp == 0) {
        float4 a0 = Tv[(size_t)node * 16 + cl * 2 + 0];
        float4 a1 = Tv[(size_t)node * 16 + cl * 2 + 1];
        const unsigned short* u0 = (const unsigned short*)&a0;
        const unsigned short* u1 = (const unsigned short*)&a1;
#pragma unroll
        for (int j = 0; j < 8; ++j) {
            acc[j] = di * bf2f(u0[j]);
            acc[8 + j] = di * bf2f(u1[j]);
        }
    } else {
#pragma unroll
        for (int j = 0; j < 16; ++j) acc[j] = 0.f;
    }

    int e0 = rowstart(rp, bsum, node);
    int e1 = (node + 1 < NN) ? rowstart(rp, bsum, node + 1) : NE;
    for (int e = e0 + grp; e < e1; e += 8) {
        int s = eidx[e];
        float ds = dinv[s];
        float4 g0 = Tv[(size_t)s * 16 + cl * 2 + 0];
        float4 g1 = Tv[(size_t)s * 16 + cl * 2 + 1];
        const unsigned short* u0 = (const unsigned short*)&g0;
        const unsigned short* u1 = (const unsigned short*)&g1;
#pragma unroll
        for (int j = 0; j < 8; ++j) {
            acc[j] += ds * bf2f(u0[j]);
            acc[8 + j] += ds * bf2f(u1[j]);
        }
    }

    // butterfly: all lanes get full 16-ch sums for their cl
#pragma unroll
    for (int j = 0; j < 16; ++j) {
        acc[j] += __shfl_xor(acc[j], 8);
        acc[j] += __shfl_xor(acc[j], 16);
        acc[j] += __shfl_xor(acc[j], 32);
    }

    // z = relu(bn(...)) for this lane's 16 channels
    float z[16];
#pragma unroll
    for (int j = 0; j < 16; ++j) {
        int ch = cl * 16 + j;
        z[j] = fmaxf(acc[j] * di * sc[ch] + sh[ch], 0.f);
    }

    // fused z @ W3: lane (cl,grp) computes partials for out cols c0=grp*2, c0+1
    int c0 = grp * 2;
    float p0 = 0.f, p1 = 0.f;
#pragma unroll
    for (int j = 0; j < 16; ++j) {
        int k = cl * 16 + j;
        float2 wv = *(const float2*)(W3 + (size_t)k * 16 + c0);
        p0 += z[j] * wv.x;
        p1 += z[j] * wv.y;
    }
    // reduce over cl (lane bits 0..2)
    p0 += __shfl_xor(p0, 1); p1 += __shfl_xor(p1, 1);
    p0 += __shfl_xor(p0, 2); p1 += __shfl_xor(p1, 2);
    p0 += __shfl_xor(p0, 4); p1 += __shfl_xor(p1, 4);

    if (cl == 0) {
        union { unsigned u; unsigned short s[2]; } pk;
        pk.s[0] = f2bf(p0);
        pk.s[1] = f2bf(p1);
        *(unsigned*)(Tc + (size_t)node * 16 + c0) = pk.u;
    }
}

// ---------------- aggregate 16ch: 8 lanes/node + lsm ----------------
__global__ __launch_bounds__(256) void k_agg16_lsm(
    const unsigned short* __restrict__ Tc, const int* __restrict__ rp,
    const int* __restrict__ bsum, const int* __restrict__ eidx,
    const float* __restrict__ dinv, const float* __restrict__ b3,
    float* __restrict__ out) {
    int node = blockIdx.x * 32 + (threadIdx.x >> 3);
    if (node >= NN) return;
    int sub = threadIdx.x & 7;
    const float4* Tv = (const float4*)Tc;
    float di = dinv[node];

    float acc[16];
    if (sub == 0) {
        float4 a0 = Tv[(size_t)node * 2 + 0];
        float4 a1 = Tv[(size_t)node * 2 + 1];
        const unsigned short* u0 = (const unsigned short*)&a0;
        const unsigned short* u1 = (const unsigned short*)&a1;
#pragma unroll
        for (int j = 0; j < 8; ++j) {
            acc[j] = di * bf2f(u0[j]);
            acc[8 + j] = di * bf2f(u1[j]);
        }
    } else {
#pragma unroll
        for (int j = 0; j < 16; ++j) acc[j] = 0.f;
    }

    int e0 = rowstart(rp, bsum, node);
    int e1 = (node + 1 < NN) ? rowstart(rp, bsum, node + 1) : NE;
    for (int e = e0 + sub; e < e1; e += 8) {
        int s = eidx[e];
        float ds = dinv[s];
        float4 g0 = Tv[(size_t)s * 2 + 0];
        float4 g1 = Tv[(size_t)s * 2 + 1];
        const unsigned short* u0 = (const unsigned short*)&g0;
        const unsigned short* u1 = (const unsigned short*)&g1;
#pragma unroll
        for (int j = 0; j < 8; ++j) {
            acc[j] += ds * bf2f(u0[j]);
            acc[8 + j] += ds * bf2f(u1[j]);
        }
    }

#pragma unroll
    for (int j = 0; j < 16; ++j) {
        acc[j] += __shfl_xor(acc[j], 1);
        acc[j] += __shfl_xor(acc[j], 2);
        acc[j] += __shfl_xor(acc[j], 4);
    }

    if (sub == 0) {
        float lg[16];
        float mx = -1e30f;
#pragma unroll
        for (int q = 0; q < 4; ++q) {
            float4 bv = ((const float4*)b3)[q];
            lg[q * 4 + 0] = acc[q * 4 + 0] * di + bv.x;
            lg[q * 4 + 1] = acc[q * 4 + 1] * di + bv.y;
            lg[q * 4 + 2] = acc[q * 4 + 2] * di + bv.z;
            lg[q * 4 + 3] = acc[q * 4 + 3] * di + bv.w;
        }
#pragma unroll
        for (int j = 0; j < 16; ++j) mx = fmaxf(mx, lg[j]);
        float se = 0.f;
#pragma unroll
        for (int j = 0; j < 16; ++j) se += expf(lg[j] - mx);
        float lse = mx + logf(se);
        float4* op = (float4*)(out + (size_t)node * 16);
        op[0] = make_float4(lg[0] - lse, lg[1] - lse, lg[2] - lse, lg[3] - lse);
        op[1] = make_float4(lg[4] - lse, lg[5] - lse, lg[6] - lse, lg[7] - lse);
        op[2] = make_float4(lg[8] - lse, lg[9] - lse, lg[10] - lse, lg[11] - lse);
        op[3] = make_float4(lg[12] - lse, lg[13] - lse, lg[14] - lse, lg[15] - lse);
    }
}

extern "C" void kernel_launch(void* const* d_in, const int* in_sizes, int n_in,
                              void* d_out, int out_size, void* d_ws, size_t ws_size,
                              hipStream_t stream) {
    const float* x  = (const float*)d_in[0];
    const int* ei   = (const int*)d_in[1];
    const float* W1 = (const float*)d_in[2];
    const float* b1 = (const float*)d_in[3];
    const float* g1 = (const float*)d_in[4];
    const float* be1 = (const float*)d_in[5];
    const float* m1 = (const float*)d_in[6];
    const float* v1 = (const float*)d_in[7];
    const float* W2 = (const float*)d_in[8];
    const float* b2 = (const float*)d_in[9];
    const float* g2 = (const float*)d_in[10];
    const float* be2 = (const float*)d_in[11];
    const float* m2 = (const float*)d_in[12];
    const float* v2 = (const float*)d_in[13];
    const float* W3 = (const float*)d_in[14];
    const float* b3 = (const float*)d_in[15];
    float* out = (float*)d_out;

    char* ws = (char*)d_ws;
    size_t off = 0;
    auto alloc = [&](size_t bytes) {
        char* p = ws + off;
        off = (off + bytes + 255) & ~255ULL;
        return p;
    };
    float* dinv  = (float*)alloc((size_t)NN * 4);
    int* degi    = (int*)alloc((size_t)NN * 4);
    int* rp      = (int*)alloc((size_t)NN * 4);
    int* bsum    = (int*)alloc(256 * 4);
    int* rank    = (int*)alloc((size_t)NE * 4);
    int* eidx    = (int*)alloc((size_t)NE * 4);
    float* sc1   = (float*)alloc(128 * 4);
    float* sh1   = (float*)alloc(128 * 4);
    float* sc2   = (float*)alloc(128 * 4);
    float* sh2   = (float*)alloc(128 * 4);
    unsigned short* TsA = (unsigned short*)alloc((size_t)NN * 128 * 2);
    unsigned short* actB = (unsigned short*)alloc((size_t)NN * 128 * 2);
    unsigned short* TcC = (unsigned short*)alloc((size_t)NN * 16 * 2);

    const int* srcp = ei;
    const int* dstp = ei + NE;

    hipMemsetAsync(degi, 0, (size_t)NN * 4, stream);

    // fused: layer-1 GEMM + degree/rank histogram
    k_gemm1_deg<<<GB1 + HB1, 256, 0, stream>>>(x, W1, TsA, dstp, degi, rank);

    // hierarchical scan (partial) + dinv + BN fold
    k_scan1<<<NB, 256, 0, stream>>>(degi, rp, bsum, dinv);
    k_scan2_bn<<<1, 256, 0, stream>>>(bsum, b1, g1, be1, m1, v1,
                                      b2, g2, be2, m2, v2, sc1, sh1, sc2, sh2);

    // CSR fill (no atomics, offsets computed inline)
    k_fill<<<HB1, 256, 0, stream>>>(srcp, dstp, rp, bsum, rank, eidx);

    // ---- layer 1 aggregate ----
    k_agg128_bnrelu<<<NN / 4, 256, 0, stream>>>(TsA, rp, bsum, eidx, dinv, sc1, sh1, actB);

    // ---- layer 2 GEMM ----
    k_mfma_gemm128<<<GB1, 256, 0, stream>>>(actB, W2, TsA);

    // ---- layer 2 aggregate + fused layer-3 GEMM ----
    k_agg128_bnrelu_g16<<<NN / 4, 256, 0, stream>>>(TsA, rp, bsum, eidx, dinv,
                                                    sc2, sh2, W3, TcC);

    // ---- layer 3 aggregate + log_softmax ----
    k_agg16_lsm<<<(NN + 31) / 32, 256, 0, stream>>>(TcC, rp, bsum, eidx, dinv, b3, out);
}

// Round 8
// 268.439 us; speedup vs baseline: 1.3128x; 1.3128x over previous
//
#include <hip/hip_runtime.h>

#define NN 50000
#define NE 800000
#define NB 196          // (NN+255)/256
#define GB1 391         // (NN+127)/128 gemm blocks in fused kernel
#define HB1 3125        // NE/256 hist blocks
#define BN_EPS 1e-5f

typedef __attribute__((ext_vector_type(8))) short short8;
typedef __attribute__((ext_vector_type(16))) float f32x16;
typedef __attribute__((ext_vector_type(4))) float f32x4;
typedef unsigned short u16;

static __device__ __forceinline__ u16 f2bf(float f) {
    union { float f; unsigned u; } v; v.f = f;
    unsigned r = (v.u + 0x7FFF + ((v.u >> 16) & 1)) >> 16;
    return (u16)r;
}
static __device__ __forceinline__ float bf2f(u16 s) {
    union { unsigned u; float f; } v; v.u = ((unsigned)s) << 16;
    return v.f;
}

// ---------------- fused: layer-1 GEMM (blocks [0,GB1)) + degree/rank hist ----------------
// GEMM writes Ts1 = bf16(X @ W1) UNSCALED (dinv unknown yet; agg1 applies dinv[s]).
__global__ __launch_bounds__(256) void k_gemm1_deg(
    const float* __restrict__ X, const float* __restrict__ W,
    u16* __restrict__ Y,
    const int* __restrict__ dst, int* __restrict__ deg, u16* __restrict__ rank) {
    __shared__ u16 Wt[128 * 136];  // [n][k]
    int t = threadIdx.x;

    if (blockIdx.x >= GB1) {
        int e = (blockIdx.x - GB1) * 256 + t;
        if (e < NE) rank[e] = (u16)atomicAdd(&deg[dst[e]], 1);
        return;
    }

    for (int i = t; i < 16384; i += 256) {
        int k = i >> 7, n = i & 127;
        Wt[n * 136 + k] = f2bf(W[i]);
    }
    __syncthreads();

    int wv = t >> 6;
    int l = t & 63;
    int l31 = l & 31;
    int khalf = l >> 5;
    int rowb = blockIdx.x * 128 + wv * 32;
    int myrow = rowb + l31;
    int rowc = myrow < NN ? myrow : NN - 1;

    f32x16 acc[4];
#pragma unroll
    for (int nt = 0; nt < 4; ++nt)
#pragma unroll
        for (int r = 0; r < 16; ++r) acc[nt][r] = 0.f;

#pragma unroll
    for (int ks = 0; ks < 8; ++ks) {
        int kk = ks * 16;
        const float* ap = X + (size_t)rowc * 128 + kk + khalf * 8;
        float4 f0 = ((const float4*)ap)[0];
        float4 f1 = ((const float4*)ap)[1];
        short8 a;
        a[0] = (short)f2bf(f0.x); a[1] = (short)f2bf(f0.y);
        a[2] = (short)f2bf(f0.z); a[3] = (short)f2bf(f0.w);
        a[4] = (short)f2bf(f1.x); a[5] = (short)f2bf(f1.y);
        a[6] = (short)f2bf(f1.z); a[7] = (short)f2bf(f1.w);
#pragma unroll
        for (int nt = 0; nt < 4; ++nt) {
            short8 b = *(const short8*)&Wt[(nt * 32 + l31) * 136 + kk + khalf * 8];
            acc[nt] = __builtin_amdgcn_mfma_f32_32x32x16_bf16(a, b, acc[nt], 0, 0, 0);
        }
    }

#pragma unroll
    for (int r = 0; r < 16; ++r) {
        int m = (r & 3) + 8 * (r >> 2) + 4 * khalf;
        int grow = rowb + m;
        if (grow < NN) {
#pragma unroll
            for (int nt = 0; nt < 4; ++nt)
                Y[(size_t)grow * 128 + nt * 32 + l31] = f2bf(acc[nt][r]);
        }
    }
}

// ---------------- hierarchical scan (196 blocks), dinv fused; rp stays PARTIAL ----------------
__global__ __launch_bounds__(256) void k_scan1(const int* __restrict__ deg,
                                               int* __restrict__ rp,
                                               int* __restrict__ bsum,
                                               float* __restrict__ dinv) {
    __shared__ int s[256];
    int t = threadIdx.x;
    int i = blockIdx.x * 256 + t;
    int v = (i < NN) ? deg[i] : 0;
    if (i < NN) dinv[i] = rsqrtf((float)(v + 1));  // +1 self-loop
    s[t] = v;
    __syncthreads();
    for (int off = 1; off < 256; off <<= 1) {
        int add = (t >= off) ? s[t - off] : 0;
        __syncthreads();
        s[t] += add;
        __syncthreads();
    }
    if (i < NN) rp[i] = s[t] - v;
    if (t == 255) bsum[blockIdx.x] = s[255];
}

__global__ __launch_bounds__(256) void k_scan2_bn(
    int* __restrict__ bsum,
    const float* b1, const float* g1, const float* be1, const float* m1, const float* v1,
    const float* b2, const float* g2, const float* be2, const float* m2, const float* v2,
    float* sc1, float* sh1, float* sc2, float* sh2) {
    __shared__ int s[256];
    int t = threadIdx.x;
    int v = (t < NB) ? bsum[t] : 0;
    s[t] = v;
    __syncthreads();
    for (int off = 1; off < 256; off <<= 1) {
        int add = (t >= off) ? s[t - off] : 0;
        __syncthreads();
        s[t] += add;
        __syncthreads();
    }
    if (t < NB) bsum[t] = s[t] - v;
    if (t < 128) {
        float s1 = rsqrtf(v1[t] + BN_EPS) * g1[t];
        sc1[t] = s1; sh1[t] = be1[t] + (b1[t] - m1[t]) * s1;
        float s2 = rsqrtf(v2[t] + BN_EPS) * g2[t];
        sc2[t] = s2; sh2[t] = be2[t] + (b2[t] - m2[t]) * s2;
    }
}

static __device__ __forceinline__ int rowstart(const int* __restrict__ rp,
                                               const int* __restrict__ bsum, int i) {
    return rp[i] + bsum[i >> 8];
}

// ---------------- CSR fill: no atomics, u16 eidx ----------------
__global__ void k_fill(const int* __restrict__ src, const int* __restrict__ dst,
                       const int* __restrict__ rp, const int* __restrict__ bsum,
                       const u16* __restrict__ rank, u16* __restrict__ eidx) {
    int e = blockIdx.x * blockDim.x + threadIdx.x;
    if (e >= NE) return;
    int d = dst[e];
    eidx[rowstart(rp, bsum, d) + (int)rank[e]] = (u16)src[e];
}

// ---------------- MFMA GEMM 128->128, epilogue scales by dinv[row] ----------------
__global__ __launch_bounds__(256) void k_mfma_gemm128(
    const u16* __restrict__ Xb, const float* __restrict__ W,
    const float* __restrict__ dinv, u16* __restrict__ Y) {
    __shared__ u16 Wt[128 * 136];
    int t = threadIdx.x;
    for (int i = t; i < 16384; i += 256) {
        int k = i >> 7, n = i & 127;
        Wt[n * 136 + k] = f2bf(W[i]);
    }
    __syncthreads();

    int wv = t >> 6;
    int l = t & 63;
    int l31 = l & 31;
    int khalf = l >> 5;
    int rowb = blockIdx.x * 128 + wv * 32;
    int myrow = rowb + l31;
    int rowc = myrow < NN ? myrow : NN - 1;

    f32x16 acc[4];
#pragma unroll
    for (int nt = 0; nt < 4; ++nt)
#pragma unroll
        for (int r = 0; r < 16; ++r) acc[nt][r] = 0.f;

#pragma unroll
    for (int ks = 0; ks < 8; ++ks) {
        int kk = ks * 16;
        short8 a = *(const short8*)(Xb + (size_t)rowc * 128 + kk + khalf * 8);
#pragma unroll
        for (int nt = 0; nt < 4; ++nt) {
            short8 b = *(const short8*)&Wt[(nt * 32 + l31) * 136 + kk + khalf * 8];
            acc[nt] = __builtin_amdgcn_mfma_f32_32x32x16_bf16(a, b, acc[nt], 0, 0, 0);
        }
    }

#pragma unroll
    for (int r = 0; r < 16; ++r) {
        int m = (r & 3) + 8 * (r >> 2) + 4 * khalf;
        int grow = rowb + m;
        if (grow < NN) {
            float dsc = dinv[grow];
#pragma unroll
            for (int nt = 0; nt < 4; ++nt)
                Y[(size_t)grow * 128 + nt * 32 + l31] = f2bf(acc[nt][r] * dsc);
        }
    }
}

// ---------------- MFMA GEMM 128->16, epilogue scales by dinv[row] ----------------
__global__ __launch_bounds__(256) void k_mfma_gemm16(
    const u16* __restrict__ Xb, const float* __restrict__ W3,
    const float* __restrict__ dinv, u16* __restrict__ Y) {
    __shared__ u16 Wt[16 * 136];
    int t = threadIdx.x;
    for (int i = t; i < 2048; i += 256) {
        int k = i >> 4, n = i & 15;
        Wt[n * 136 + k] = f2bf(W3[i]);
    }
    __syncthreads();

    int wv = t >> 6;
    int l = t & 63;
    int l15 = l & 15;
    int quad = l >> 4;
    int rowb = blockIdx.x * 256 + wv * 64;

    f32x4 acc[4];
#pragma unroll
    for (int mt = 0; mt < 4; ++mt)
#pragma unroll
        for (int r = 0; r < 4; ++r) acc[mt][r] = 0.f;

#pragma unroll
    for (int ks = 0; ks < 4; ++ks) {
        int kk = ks * 32;
        short8 b = *(const short8*)&Wt[l15 * 136 + kk + quad * 8];
#pragma unroll
        for (int mt = 0; mt < 4; ++mt) {
            int row = rowb + mt * 16 + l15;
            int rowc = row < NN ? row : NN - 1;
            short8 a = *(const short8*)(Xb + (size_t)rowc * 128 + kk + quad * 8);
            acc[mt] = __builtin_amdgcn_mfma_f32_16x16x32_bf16(a, b, acc[mt], 0, 0, 0);
        }
    }

#pragma unroll
    for (int mt = 0; mt < 4; ++mt) {
#pragma unroll
        for (int r = 0; r < 4; ++r) {
            int grow = rowb + mt * 16 + quad * 4 + r;
            if (grow < NN)
                Y[(size_t)grow * 16 + l15] = f2bf(acc[mt][r] * dinv[grow]);
        }
    }
}

// ---------------- agg layer-1: Ts1 unscaled -> needs dinv[s]; prefetch depth 1 ----------------
__global__ __launch_bounds__(256) void k_agg1(
    const u16* __restrict__ Ts, const int* __restrict__ rp,
    const int* __restrict__ bsum, const u16* __restrict__ eidx,
    const float* __restrict__ dinv,
    const float* __restrict__ sc, const float* __restrict__ sh,
    u16* __restrict__ Z) {
    int node = blockIdx.x * 4 + (threadIdx.x >> 6);
    int l = threadIdx.x & 63;
    int grp = l >> 3;       // edge slot 0..7 (lane bits 3..5)
    int cl = l & 7;         // channel chunk (16 ch)
    const float4* Tv = (const float4*)Ts;
    float di = dinv[node];

    float acc[16];
    if (grp == 0) {
        float4 a0 = Tv[(size_t)node * 16 + cl * 2 + 0];
        float4 a1 = Tv[(size_t)node * 16 + cl * 2 + 1];
        const u16* u0 = (const u16*)&a0;
        const u16* u1 = (const u16*)&a1;
#pragma unroll
        for (int j = 0; j < 8; ++j) {
            acc[j] = di * bf2f(u0[j]);
            acc[8 + j] = di * bf2f(u1[j]);
        }
    } else {
#pragma unroll
        for (int j = 0; j < 16; ++j) acc[j] = 0.f;
    }

    int e0 = rowstart(rp, bsum, node);
    int e1 = (node + 1 < NN) ? rowstart(rp, bsum, node + 1) : NE;
    int e = e0 + grp;
    int s = (e < e1) ? (int)eidx[e] : -1;
    while (s >= 0) {
        e += 8;
        int sn = (e < e1) ? (int)eidx[e] : -1;  // prefetch next index
        float ds = dinv[s];
        float4 g0 = Tv[(size_t)s * 16 + cl * 2 + 0];
        float4 g1 = Tv[(size_t)s * 16 + cl * 2 + 1];
        const u16* u0 = (const u16*)&g0;
        const u16* u1 = (const u16*)&g1;
#pragma unroll
        for (int j = 0; j < 8; ++j) {
            acc[j] += ds * bf2f(u0[j]);
            acc[8 + j] += ds * bf2f(u1[j]);
        }
        s = sn;
    }

#pragma unroll
    for (int j = 0; j < 16; ++j) {
        acc[j] += __shfl_xor(acc[j], 8);
        acc[j] += __shfl_xor(acc[j], 16);
        acc[j] += __shfl_xor(acc[j], 32);
    }

    if (grp < 2) {  // 16 writer lanes, one float4 (8 ch) each
        int h = grp;
        float4 o;
        u16* ov = (u16*)&o;
#pragma unroll
        for (int j = 0; j < 8; ++j) {
            int ch = cl * 16 + h * 8 + j;
            ov[j] = f2bf(fmaxf(acc[h * 8 + j] * di * sc[ch] + sh[ch], 0.f));
        }
        ((float4*)Z)[(size_t)node * 16 + cl * 2 + h] = o;
    }
}

// ---------------- agg layer-2: Ts2 pre-scaled -> no dinv[s]; prefetch depth 1 ----------------
__global__ __launch_bounds__(256) void k_agg2(
    const u16* __restrict__ Ts, const int* __restrict__ rp,
    const int* __restrict__ bsum, const u16* __restrict__ eidx,
    const float* __restrict__ dinv,
    const float* __restrict__ sc, const float* __restrict__ sh,
    u16* __restrict__ Z) {
    int node = blockIdx.x * 4 + (threadIdx.x >> 6);
    int l = threadIdx.x & 63;
    int grp = l >> 3;
    int cl = l & 7;
    const float4* Tv = (const float4*)Ts;
    float di = dinv[node];

    float acc[16];
    if (grp == 0) {  // self term: rows already carry dinv[row]
        float4 a0 = Tv[(size_t)node * 16 + cl * 2 + 0];
        float4 a1 = Tv[(size_t)node * 16 + cl * 2 + 1];
        const u16* u0 = (const u16*)&a0;
        const u16* u1 = (const u16*)&a1;
#pragma unroll
        for (int j = 0; j < 8; ++j) {
            acc[j] = bf2f(u0[j]);
            acc[8 + j] = bf2f(u1[j]);
        }
    } else {
#pragma unroll
        for (int j = 0; j < 16; ++j) acc[j] = 0.f;
    }

    int e0 = rowstart(rp, bsum, node);
    int e1 = (node + 1 < NN) ? rowstart(rp, bsum, node + 1) : NE;
    int e = e0 + grp;
    int s = (e < e1) ? (int)eidx[e] : -1;
    while (s >= 0) {
        e += 8;
        int sn = (e < e1) ? (int)eidx[e] : -1;
        float4 g0 = Tv[(size_t)s * 16 + cl * 2 + 0];
        float4 g1 = Tv[(size_t)s * 16 + cl * 2 + 1];
        const u16* u0 = (const u16*)&g0;
        const u16* u1 = (const u16*)&g1;
#pragma unroll
        for (int j = 0; j < 8; ++j) {
            acc[j] += bf2f(u0[j]);
            acc[8 + j] += bf2f(u1[j]);
        }
        s = sn;
    }

#pragma unroll
    for (int j = 0; j < 16; ++j) {
        acc[j] += __shfl_xor(acc[j], 8);
        acc[j] += __shfl_xor(acc[j], 16);
        acc[j] += __shfl_xor(acc[j], 32);
    }

    if (grp < 2) {
        int h = grp;
        float4 o;
        u16* ov = (u16*)&o;
#pragma unroll
        for (int j = 0; j < 8; ++j) {
            int ch = cl * 16 + h * 8 + j;
            ov[j] = f2bf(fmaxf(acc[h * 8 + j] * di * sc[ch] + sh[ch], 0.f));
        }
        ((float4*)Z)[(size_t)node * 16 + cl * 2 + h] = o;
    }
}

// ---------------- agg 16ch: Tc pre-scaled -> no dinv[s]; 8 lanes/node + lsm ----------------
__global__ __launch_bounds__(256) void k_agg16_lsm(
    const u16* __restrict__ Tc, const int* __restrict__ rp,
    const int* __restrict__ bsum, const u16* __restrict__ eidx,
    const float* __restrict__ dinv, const float* __restrict__ b3,
    float* __restrict__ out) {
    int node = blockIdx.x * 32 + (threadIdx.x >> 3);
    if (node >= NN) return;
    int sub = threadIdx.x & 7;
    const float4* Tv = (const float4*)Tc;
    float di = dinv[node];

    float acc[16];
    if (sub == 0) {
        float4 a0 = Tv[(size_t)node * 2 + 0];
        float4 a1 = Tv[(size_t)node * 2 + 1];
        const u16* u0 = (const u16*)&a0;
        const u16* u1 = (const u16*)&a1;
#pragma unroll
        for (int j = 0; j < 8; ++j) {
            acc[j] = bf2f(u0[j]);
            acc[8 + j] = bf2f(u1[j]);
        }
    } else {
#pragma unroll
        for (int j = 0; j < 16; ++j) acc[j] = 0.f;
    }

    int e0 = rowstart(rp, bsum, node);
    int e1 = (node + 1 < NN) ? rowstart(rp, bsum, node + 1) : NE;
    int e = e0 + sub;
    int s = (e < e1) ? (int)eidx[e] : -1;
    while (s >= 0) {
        e += 8;
        int sn = (e < e1) ? (int)eidx[e] : -1;
        float4 g0 = Tv[(size_t)s * 2 + 0];
        float4 g1 = Tv[(size_t)s * 2 + 1];
        const u16* u0 = (const u16*)&g0;
        const u16* u1 = (const u16*)&g1;
#pragma unroll
        for (int j = 0; j < 8; ++j) {
            acc[j] += bf2f(u0[j]);
            acc[8 + j] += bf2f(u1[j]);
        }
        s = sn;
    }

#pragma unroll
    for (int j = 0; j < 16; ++j) {
        acc[j] += __shfl_xor(acc[j], 1);
        acc[j] += __shfl_xor(acc[j], 2);
        acc[j] += __shfl_xor(acc[j], 4);
    }

    if (sub == 0) {
        float lg[16];
        float mx = -1e30f;
#pragma unroll
        for (int q = 0; q < 4; ++q) {
            float4 bv = ((const float4*)b3)[q];
            lg[q * 4 + 0] = acc[q * 4 + 0] * di + bv.x;
            lg[q * 4 + 1] = acc[q * 4 + 1] * di + bv.y;
            lg[q * 4 + 2] = acc[q * 4 + 2] * di + bv.z;
            lg[q * 4 + 3] = acc[q * 4 + 3] * di + bv.w;
        }
#pragma unroll
        for (int j = 0; j < 16; ++j) mx = fmaxf(mx, lg[j]);
        float se = 0.f;
#pragma unroll
        for (int j = 0; j < 16; ++j) se += expf(lg[j] - mx);
        float lse = mx + logf(se);
        float4* op = (float4*)(out + (size_t)node * 16);
        op[0] = make_float4(lg[0] - lse, lg[1] - lse, lg[2] - lse, lg[3] - lse);
        op[1] = make_float4(lg[4] - lse, lg[5] - lse, lg[6] - lse, lg[7] - lse);
        op[2] = make_float4(lg[8] - lse, lg[9] - lse, lg[10] - lse, lg[11] - lse);
        op[3] = make_float4(lg[12] - lse, lg[13] - lse, lg[14] - lse, lg[15] - lse);
    }
}

extern "C" void kernel_launch(void* const* d_in, const int* in_sizes, int n_in,
                              void* d_out, int out_size, void* d_ws, size_t ws_size,
                              hipStream_t stream) {
    const float* x  = (const float*)d_in[0];
    const int* ei   = (const int*)d_in[1];
    const float* W1 = (const float*)d_in[2];
    const float* b1 = (const float*)d_in[3];
    const float* g1 = (const float*)d_in[4];
    const float* be1 = (const float*)d_in[5];
    const float* m1 = (const float*)d_in[6];
    const float* v1 = (const float*)d_in[7];
    const float* W2 = (const float*)d_in[8];
    const float* b2 = (const float*)d_in[9];
    const float* g2 = (const float*)d_in[10];
    const float* be2 = (const float*)d_in[11];
    const float* m2 = (const float*)d_in[12];
    const float* v2 = (const float*)d_in[13];
    const float* W3 = (const float*)d_in[14];
    const float* b3 = (const float*)d_in[15];
    float* out = (float*)d_out;

    char* ws = (char*)d_ws;
    size_t off = 0;
    auto alloc = [&](size_t bytes) {
        char* p = ws + off;
        off = (off + bytes + 255) & ~255ULL;
        return p;
    };
    float* dinv  = (float*)alloc((size_t)NN * 4);
    int* degi    = (int*)alloc((size_t)NN * 4);
    int* rp      = (int*)alloc((size_t)NN * 4);
    int* bsum    = (int*)alloc(256 * 4);
    u16* rank    = (u16*)alloc((size_t)NE * 2);
    u16* eidx    = (u16*)alloc((size_t)NE * 2);
    float* sc1   = (float*)alloc(128 * 4);
    float* sh1   = (float*)alloc(128 * 4);
    float* sc2   = (float*)alloc(128 * 4);
    float* sh2   = (float*)alloc(128 * 4);
    u16* TsA  = (u16*)alloc((size_t)NN * 128 * 2);
    u16* actB = (u16*)alloc((size_t)NN * 128 * 2);
    u16* TcC  = (u16*)alloc((size_t)NN * 16 * 2);

    const int* srcp = ei;
    const int* dstp = ei + NE;

    hipMemsetAsync(degi, 0, (size_t)NN * 4, stream);

    // fused: layer-1 GEMM + degree/rank histogram
    k_gemm1_deg<<<GB1 + HB1, 256, 0, stream>>>(x, W1, TsA, dstp, degi, rank);

    // hierarchical scan (partial) + dinv + BN fold
    k_scan1<<<NB, 256, 0, stream>>>(degi, rp, bsum, dinv);
    k_scan2_bn<<<1, 256, 0, stream>>>(bsum, b1, g1, be1, m1, v1,
                                      b2, g2, be2, m2, v2, sc1, sh1, sc2, sh2);

    // CSR fill (no atomics, u16)
    k_fill<<<HB1, 256, 0, stream>>>(srcp, dstp, rp, bsum, rank, eidx);

    // ---- layer 1 aggregate (Ts1 unscaled) ----
    k_agg1<<<NN / 4, 256, 0, stream>>>(TsA, rp, bsum, eidx, dinv, sc1, sh1, actB);

    // ---- layer 2: GEMM (pre-scaled by dinv) + aggregate ----
    k_mfma_gemm128<<<GB1, 256, 0, stream>>>(actB, W2, dinv, TsA);
    k_agg2<<<NN / 4, 256, 0, stream>>>(TsA, rp, bsum, eidx, dinv, sc2, sh2, actB);

    // ---- layer 3: GEMM (pre-scaled) + aggregate + log_softmax ----
    k_mfma_gemm16<<<(NN + 255) / 256, 256, 0, stream>>>(actB, W3, dinv, TcC);
    k_agg16_lsm<<<(NN + 31) / 32, 256, 0, stream>>>(TcC, rp, bsum, eidx, dinv, b3, out);
}

// Round 9
// 260.379 us; speedup vs baseline: 1.3534x; 1.0310x over previous
//
#include <hip/hip_runtime.h>
#include <hip/hip_fp16.h>

#define NN 50000
#define NE 800000
#define NB 196          // (NN+255)/256
#define GB1 391         // (NN+127)/128 gemm blocks in fused kernel
#define HB 782          // hist blocks: 782*256*4 >= NE
#define FB 3125         // NE/256 fill blocks
#define BN_EPS 1e-5f

typedef __attribute__((ext_vector_type(8))) _Float16 f16x8;
typedef __attribute__((ext_vector_type(16))) float f32x16;
typedef __attribute__((ext_vector_type(4))) float f32x4;
typedef unsigned short u16;

static __device__ __forceinline__ __half2 h2shfl_xor(__half2 v, int m) {
    union { __half2 h; int i; } u; u.h = v;
    u.i = __shfl_xor(u.i, m);
    return u.h;
}

// ---------------- fused: layer-1 GEMM (blocks [0,GB1)) + degree/rank hist ----------------
// GEMM writes Ts1 = f16(X @ W1) UNSCALED (dinv unknown yet; agg1 applies dinv[s]).
__global__ __launch_bounds__(256) void k_gemm1_deg(
    const float* __restrict__ X, const float* __restrict__ W,
    _Float16* __restrict__ Y,
    const int* __restrict__ dst, int* __restrict__ deg, u16* __restrict__ rank) {
    __shared__ _Float16 Wt[128 * 136];  // [n][k]
    int t = threadIdx.x;

    if (blockIdx.x >= GB1) {
        int e = (blockIdx.x - GB1) * 256 + t;
#pragma unroll
        for (int j = 0; j < 4; ++j) {
            int idx = e + j * (HB * 256);
            if (idx < NE) rank[idx] = (u16)atomicAdd(&deg[dst[idx]], 1);
        }
        return;
    }

    for (int i = t; i < 16384; i += 256) {
        int k = i >> 7, n = i & 127;
        Wt[n * 136 + k] = (_Float16)W[i];
    }
    __syncthreads();

    int wv = t >> 6;
    int l = t & 63;
    int l31 = l & 31;
    int khalf = l >> 5;
    int rowb = blockIdx.x * 128 + wv * 32;
    int myrow = rowb + l31;
    int rowc = myrow < NN ? myrow : NN - 1;

    f32x16 acc[4];
#pragma unroll
    for (int nt = 0; nt < 4; ++nt)
#pragma unroll
        for (int r = 0; r < 16; ++r) acc[nt][r] = 0.f;

#pragma unroll
    for (int ks = 0; ks < 8; ++ks) {
        int kk = ks * 16;
        const float* ap = X + (size_t)rowc * 128 + kk + khalf * 8;
        float4 f0 = ((const float4*)ap)[0];
        float4 f1 = ((const float4*)ap)[1];
        f16x8 a;
        a[0] = (_Float16)f0.x; a[1] = (_Float16)f0.y;
        a[2] = (_Float16)f0.z; a[3] = (_Float16)f0.w;
        a[4] = (_Float16)f1.x; a[5] = (_Float16)f1.y;
        a[6] = (_Float16)f1.z; a[7] = (_Float16)f1.w;
#pragma unroll
        for (int nt = 0; nt < 4; ++nt) {
            f16x8 b = *(const f16x8*)&Wt[(nt * 32 + l31) * 136 + kk + khalf * 8];
            acc[nt] = __builtin_amdgcn_mfma_f32_32x32x16_f16(a, b, acc[nt], 0, 0, 0);
        }
    }

#pragma unroll
    for (int r = 0; r < 16; ++r) {
        int m = (r & 3) + 8 * (r >> 2) + 4 * khalf;
        int grow = rowb + m;
        if (grow < NN) {
#pragma unroll
            for (int nt = 0; nt < 4; ++nt)
                Y[(size_t)grow * 128 + nt * 32 + l31] = (_Float16)acc[nt][r];
        }
    }
}

// ---------------- hierarchical scan (196 blocks), dinv fused; rp stays PARTIAL ----------------
__global__ __launch_bounds__(256) void k_scan1(const int* __restrict__ deg,
                                               int* __restrict__ rp,
                                               int* __restrict__ bsum,
                                               float* __restrict__ dinv) {
    __shared__ int s[256];
    int t = threadIdx.x;
    int i = blockIdx.x * 256 + t;
    int v = (i < NN) ? deg[i] : 0;
    if (i < NN) dinv[i] = rsqrtf((float)(v + 1));  // +1 self-loop
    s[t] = v;
    __syncthreads();
    for (int off = 1; off < 256; off <<= 1) {
        int add = (t >= off) ? s[t - off] : 0;
        __syncthreads();
        s[t] += add;
        __syncthreads();
    }
    if (i < NN) rp[i] = s[t] - v;
    if (t == 255) bsum[blockIdx.x] = s[255];
}

__global__ __launch_bounds__(256) void k_scan2_bn(
    int* __restrict__ bsum,
    const float* b1, const float* g1, const float* be1, const float* m1, const float* v1,
    const float* b2, const float* g2, const float* be2, const float* m2, const float* v2,
    float* sc1, float* sh1, float* sc2, float* sh2) {
    __shared__ int s[256];
    int t = threadIdx.x;
    int v = (t < NB) ? bsum[t] : 0;
    s[t] = v;
    __syncthreads();
    for (int off = 1; off < 256; off <<= 1) {
        int add = (t >= off) ? s[t - off] : 0;
        __syncthreads();
        s[t] += add;
        __syncthreads();
    }
    if (t < NB) bsum[t] = s[t] - v;
    if (t < 128) {
        float s1 = rsqrtf(v1[t] + BN_EPS) * g1[t];
        sc1[t] = s1; sh1[t] = be1[t] + (b1[t] - m1[t]) * s1;
        float s2 = rsqrtf(v2[t] + BN_EPS) * g2[t];
        sc2[t] = s2; sh2[t] = be2[t] + (b2[t] - m2[t]) * s2;
    }
}

static __device__ __forceinline__ int rowstart(const int* __restrict__ rp,
                                               const int* __restrict__ bsum, int i) {
    return rp[i] + bsum[i >> 8];
}

// ---------------- CSR fill: no atomics, u16 eidx ----------------
__global__ void k_fill(const int* __restrict__ src, const int* __restrict__ dst,
                       const int* __restrict__ rp, const int* __restrict__ bsum,
                       const u16* __restrict__ rank, u16* __restrict__ eidx) {
    int e = blockIdx.x * blockDim.x + threadIdx.x;
    if (e >= NE) return;
    int d = dst[e];
    eidx[rowstart(rp, bsum, d) + (int)rank[e]] = (u16)src[e];
}

// ---------------- MFMA GEMM 128->128 f16, epilogue scales by dinv[row] ----------------
__global__ __launch_bounds__(256) void k_mfma_gemm128(
    const _Float16* __restrict__ Xb, const float* __restrict__ W,
    const float* __restrict__ dinv, _Float16* __restrict__ Y) {
    __shared__ _Float16 Wt[128 * 136];
    int t = threadIdx.x;
    for (int i = t; i < 16384; i += 256) {
        int k = i >> 7, n = i & 127;
        Wt[n * 136 + k] = (_Float16)W[i];
    }
    __syncthreads();

    int wv = t >> 6;
    int l = t & 63;
    int l31 = l & 31;
    int khalf = l >> 5;
    int rowb = blockIdx.x * 128 + wv * 32;
    int myrow = rowb + l31;
    int rowc = myrow < NN ? myrow : NN - 1;

    f32x16 acc[4];
#pragma unroll
    for (int nt = 0; nt < 4; ++nt)
#pragma unroll
        for (int r = 0; r < 16; ++r) acc[nt][r] = 0.f;

#pragma unroll
    for (int ks = 0; ks < 8; ++ks) {
        int kk = ks * 16;
        f16x8 a = *(const f16x8*)(Xb + (size_t)rowc * 128 + kk + khalf * 8);
#pragma unroll
        for (int nt = 0; nt < 4; ++nt) {
            f16x8 b = *(const f16x8*)&Wt[(nt * 32 + l31) * 136 + kk + khalf * 8];
            acc[nt] = __builtin_amdgcn_mfma_f32_32x32x16_f16(a, b, acc[nt], 0, 0, 0);
        }
    }

#pragma unroll
    for (int r = 0; r < 16; ++r) {
        int m = (r & 3) + 8 * (r >> 2) + 4 * khalf;
        int grow = rowb + m;
        if (grow < NN) {
            float dsc = dinv[grow];
#pragma unroll
            for (int nt = 0; nt < 4; ++nt)
                Y[(size_t)grow * 128 + nt * 32 + l31] = (_Float16)(acc[nt][r] * dsc);
        }
    }
}

// ---------------- MFMA GEMM 128->16 f16, epilogue scales by dinv[row] ----------------
__global__ __launch_bounds__(256) void k_mfma_gemm16(
    const _Float16* __restrict__ Xb, const float* __restrict__ W3,
    const float* __restrict__ dinv, _Float16* __restrict__ Y) {
    __shared__ _Float16 Wt[16 * 136];
    int t = threadIdx.x;
    for (int i = t; i < 2048; i += 256) {
        int k = i >> 4, n = i & 15;
        Wt[n * 136 + k] = (_Float16)W3[i];
    }
    __syncthreads();

    int wv = t >> 6;
    int l = t & 63;
    int l15 = l & 15;
    int quad = l >> 4;
    int rowb = blockIdx.x * 256 + wv * 64;

    f32x4 acc[4];
#pragma unroll
    for (int mt = 0; mt < 4; ++mt)
#pragma unroll
        for (int r = 0; r < 4; ++r) acc[mt][r] = 0.f;

#pragma unroll
    for (int ks = 0; ks < 4; ++ks) {
        int kk = ks * 32;
        f16x8 b = *(const f16x8*)&Wt[l15 * 136 + kk + quad * 8];
#pragma unroll
        for (int mt = 0; mt < 4; ++mt) {
            int row = rowb + mt * 16 + l15;
            int rowc = row < NN ? row : NN - 1;
            f16x8 a = *(const f16x8*)(Xb + (size_t)rowc * 128 + kk + quad * 8);
            acc[mt] = __builtin_amdgcn_mfma_f32_16x16x32_f16(a, b, acc[mt], 0, 0, 0);
        }
    }

#pragma unroll
    for (int mt = 0; mt < 4; ++mt) {
#pragma unroll
        for (int r = 0; r < 4; ++r) {
            int grow = rowb + mt * 16 + quad * 4 + r;
            if (grow < NN)
                Y[(size_t)grow * 16 + l15] = (_Float16)(acc[mt][r] * dinv[grow]);
        }
    }
}

// ---------------- agg layer-1: 4 slots x 16 ch-lanes, packed f16 math, dinv[s] weights ----------------
__global__ __launch_bounds__(256) void k_agg1(
    const _Float16* __restrict__ Ts, const int* __restrict__ rp,
    const int* __restrict__ bsum, const u16* __restrict__ eidx,
    const float* __restrict__ dinv,
    const float* __restrict__ sc, const float* __restrict__ sh,
    _Float16* __restrict__ Z) {
    int node = blockIdx.x * 4 + (threadIdx.x >> 6);
    int l = threadIdx.x & 63;
    int grp = l >> 4;       // edge slot 0..3 (lane bits 4,5)
    int cl = l & 15;        // channel chunk: 8 ch (one float4 of f16)
    const float4* Tv = (const float4*)Ts;
    float di = dinv[node];

    __half2 acc[4];
    if (grp == 0) {
        float4 a0 = Tv[(size_t)node * 16 + cl];
        const __half2* hp = (const __half2*)&a0;
        __half2 div2 = __float2half2_rn(di);
#pragma unroll
        for (int j = 0; j < 4; ++j) acc[j] = __hmul2(hp[j], div2);
    } else {
        __half2 z = __float2half2_rn(0.f);
#pragma unroll
        for (int j = 0; j < 4; ++j) acc[j] = z;
    }

    int e0 = rowstart(rp, bsum, node);
    int e1 = (node + 1 < NN) ? rowstart(rp, bsum, node + 1) : NE;
    for (int e = e0 + grp; e < e1; e += 4) {
        int s = (int)eidx[e];
        __half2 dsv = __float2half2_rn(dinv[s]);
        float4 g = Tv[(size_t)s * 16 + cl];
        const __half2* hp = (const __half2*)&g;
#pragma unroll
        for (int j = 0; j < 4; ++j) acc[j] = __hfma2(hp[j], dsv, acc[j]);
    }

    // reduce across the 4 edge slots (lane bits 4,5)
#pragma unroll
    for (int j = 0; j < 4; ++j) {
        acc[j] = __hadd2(acc[j], h2shfl_xor(acc[j], 16));
        acc[j] = __hadd2(acc[j], h2shfl_xor(acc[j], 32));
    }

    if (grp == 0) {
        float4 scv0 = ((const float4*)sc)[cl * 2 + 0];
        float4 scv1 = ((const float4*)sc)[cl * 2 + 1];
        float4 shv0 = ((const float4*)sh)[cl * 2 + 0];
        float4 shv1 = ((const float4*)sh)[cl * 2 + 1];
        const float* scl = (const float*)&scv0;  // scv0/scv1 contiguous? build arrays safely:
        float sca[8] = {scv0.x, scv0.y, scv0.z, scv0.w, scv1.x, scv1.y, scv1.z, scv1.w};
        float sha[8] = {shv0.x, shv0.y, shv0.z, shv0.w, shv1.x, shv1.y, shv1.z, shv1.w};
        (void)scl;
        float4 o;
        _Float16* ov = (_Float16*)&o;
#pragma unroll
        for (int j = 0; j < 4; ++j) {
            float2 f = __half22float2(acc[j]);
            ov[j * 2 + 0] = (_Float16)fmaxf(f.x * di * sca[j * 2 + 0] + sha[j * 2 + 0], 0.f);
            ov[j * 2 + 1] = (_Float16)fmaxf(f.y * di * sca[j * 2 + 1] + sha[j * 2 + 1], 0.f);
        }
        ((float4*)Z)[(size_t)node * 16 + cl] = o;
    }
}

// ---------------- agg layer-2: pre-scaled rows, packed adds ----------------
__global__ __launch_bounds__(256) void k_agg2(
    const _Float16* __restrict__ Ts, const int* __restrict__ rp,
    const int* __restrict__ bsum, const u16* __restrict__ eidx,
    const float* __restrict__ dinv,
    const float* __restrict__ sc, const float* __restrict__ sh,
    _Float16* __restrict__ Z) {
    int node = blockIdx.x * 4 + (threadIdx.x >> 6);
    int l = threadIdx.x & 63;
    int grp = l >> 4;
    int cl = l & 15;
    const float4* Tv = (const float4*)Ts;
    float di = dinv[node];

    __half2 acc[4];
    if (grp == 0) {
        float4 a0 = Tv[(size_t)node * 16 + cl];
        const __half2* hp = (const __half2*)&a0;
#pragma unroll
        for (int j = 0; j < 4; ++j) acc[j] = hp[j];
    } else {
        __half2 z = __float2half2_rn(0.f);
#pragma unroll
        for (int j = 0; j < 4; ++j) acc[j] = z;
    }

    int e0 = rowstart(rp, bsum, node);
    int e1 = (node + 1 < NN) ? rowstart(rp, bsum, node + 1) : NE;
    for (int e = e0 + grp; e < e1; e += 4) {
        int s = (int)eidx[e];
        float4 g = Tv[(size_t)s * 16 + cl];
        const __half2* hp = (const __half2*)&g;
#pragma unroll
        for (int j = 0; j < 4; ++j) acc[j] = __hadd2(acc[j], hp[j]);
    }

#pragma unroll
    for (int j = 0; j < 4; ++j) {
        acc[j] = __hadd2(acc[j], h2shfl_xor(acc[j], 16));
        acc[j] = __hadd2(acc[j], h2shfl_xor(acc[j], 32));
    }

    if (grp == 0) {
        float4 scv0 = ((const float4*)sc)[cl * 2 + 0];
        float4 scv1 = ((const float4*)sc)[cl * 2 + 1];
        float4 shv0 = ((const float4*)sh)[cl * 2 + 0];
        float4 shv1 = ((const float4*)sh)[cl * 2 + 1];
        float sca[8] = {scv0.x, scv0.y, scv0.z, scv0.w, scv1.x, scv1.y, scv1.z, scv1.w};
        float sha[8] = {shv0.x, shv0.y, shv0.z, shv0.w, shv1.x, shv1.y, shv1.z, shv1.w};
        float4 o;
        _Float16* ov = (_Float16*)&o;
#pragma unroll
        for (int j = 0; j < 4; ++j) {
            float2 f = __half22float2(acc[j]);
            ov[j * 2 + 0] = (_Float16)fmaxf(f.x * di * sca[j * 2 + 0] + sha[j * 2 + 0], 0.f);
            ov[j * 2 + 1] = (_Float16)fmaxf(f.y * di * sca[j * 2 + 1] + sha[j * 2 + 1], 0.f);
        }
        ((float4*)Z)[(size_t)node * 16 + cl] = o;
    }
}

// ---------------- agg 16ch: 8 lanes/node (4 slots x 2 ch-halves), packed adds + lsm ----------------
__global__ __launch_bounds__(256) void k_agg16_lsm(
    const _Float16* __restrict__ Tc, const int* __restrict__ rp,
    const int* __restrict__ bsum, const u16* __restrict__ eidx,
    const float* __restrict__ dinv, const float* __restrict__ b3,
    float* __restrict__ out) {
    int node = blockIdx.x * 32 + (threadIdx.x >> 3);
    if (node >= NN) return;
    int sub = threadIdx.x & 7;
    int grp = sub >> 1;     // slot 0..3 (lane bits 1,2)
    int half = sub & 1;     // 8-ch half
    const float4* Tv = (const float4*)Tc;
    float di = dinv[node];

    __half2 acc[4];
    if (grp == 0) {
        float4 a0 = Tv[(size_t)node * 2 + half];
        const __half2* hp = (const __half2*)&a0;
#pragma unroll
        for (int j = 0; j < 4; ++j) acc[j] = hp[j];
    } else {
        __half2 z = __float2half2_rn(0.f);
#pragma unroll
        for (int j = 0; j < 4; ++j) acc[j] = z;
    }

    int e0 = rowstart(rp, bsum, node);
    int e1 = (node + 1 < NN) ? rowstart(rp, bsum, node + 1) : NE;
    for (int e = e0 + grp; e < e1; e += 4) {
        int s = (int)eidx[e];
        float4 g = Tv[(size_t)s * 2 + half];
        const __half2* hp = (const __half2*)&g;
#pragma unroll
        for (int j = 0; j < 4; ++j) acc[j] = __hadd2(acc[j], hp[j]);
    }

    // reduce slots (lane bits 1,2)
#pragma unroll
    for (int j = 0; j < 4; ++j) {
        acc[j] = __hadd2(acc[j], h2shfl_xor(acc[j], 2));
        acc[j] = __hadd2(acc[j], h2shfl_xor(acc[j], 4));
    }

    // pull the other half's accs (lane bit 0)
    float lg[16];
#pragma unroll
    for (int j = 0; j < 4; ++j) {
        float2 mine = __half22float2(acc[j]);
        __half2 oth = h2shfl_xor(acc[j], 1);
        float2 of = __half22float2(oth);
        lg[j * 2 + 0] = mine.x;
        lg[j * 2 + 1] = mine.y;
        lg[8 + j * 2 + 0] = of.x;
        lg[8 + j * 2 + 1] = of.y;
    }

    if (sub == 0) {
        float mx = -1e30f;
#pragma unroll
        for (int j = 0; j < 16; ++j) {
            lg[j] = lg[j] * di + b3[j];
            mx = fmaxf(mx, lg[j]);
        }
        float se = 0.f;
#pragma unroll
        for (int j = 0; j < 16; ++j) se += expf(lg[j] - mx);
        float lse = mx + logf(se);
        float4* op = (float4*)(out + (size_t)node * 16);
        op[0] = make_float4(lg[0] - lse, lg[1] - lse, lg[2] - lse, lg[3] - lse);
        op[1] = make_float4(lg[4] - lse, lg[5] - lse, lg[6] - lse, lg[7] - lse);
        op[2] = make_float4(lg[8] - lse, lg[9] - lse, lg[10] - lse, lg[11] - lse);
        op[3] = make_float4(lg[12] - lse, lg[13] - lse, lg[14] - lse, lg[15] - lse);
    }
}

extern "C" void kernel_launch(void* const* d_in, const int* in_sizes, int n_in,
                              void* d_out, int out_size, void* d_ws, size_t ws_size,
                              hipStream_t stream) {
    const float* x  = (const float*)d_in[0];
    const int* ei   = (const int*)d_in[1];
    const float* W1 = (const float*)d_in[2];
    const float* b1 = (const float*)d_in[3];
    const float* g1 = (const float*)d_in[4];
    const float* be1 = (const float*)d_in[5];
    const float* m1 = (const float*)d_in[6];
    const float* v1 = (const float*)d_in[7];
    const float* W2 = (const float*)d_in[8];
    const float* b2 = (const float*)d_in[9];
    const float* g2 = (const float*)d_in[10];
    const float* be2 = (const float*)d_in[11];
    const float* m2 = (const float*)d_in[12];
    const float* v2 = (const float*)d_in[13];
    const float* W3 = (const float*)d_in[14];
    const float* b3 = (const float*)d_in[15];
    float* out = (float*)d_out;

    char* ws = (char*)d_ws;
    size_t off = 0;
    auto alloc = [&](size_t bytes) {
        char* p = ws + off;
        off = (off + bytes + 255) & ~255ULL;
        return p;
    };
    float* dinv  = (float*)alloc((size_t)NN * 4);
    int* degi    = (int*)alloc((size_t)NN * 4);
    int* rp      = (int*)alloc((size_t)NN * 4);
    int* bsum    = (int*)alloc(256 * 4);
    u16* rank    = (u16*)alloc((size_t)NE * 2);
    u16* eidx    = (u16*)alloc((size_t)NE * 2);
    float* sc1   = (float*)alloc(128 * 4);
    float* sh1   = (float*)alloc(128 * 4);
    float* sc2   = (float*)alloc(128 * 4);
    float* sh2   = (float*)alloc(128 * 4);
    _Float16* TsA  = (_Float16*)alloc((size_t)NN * 128 * 2);
    _Float16* actB = (_Float16*)alloc((size_t)NN * 128 * 2);
    _Float16* TcC  = (_Float16*)alloc((size_t)NN * 16 * 2);

    const int* srcp = ei;
    const int* dstp = ei + NE;

    hipMemsetAsync(degi, 0, (size_t)NN * 4, stream);

    // fused: layer-1 GEMM + degree/rank histogram (4 edges/thread)
    k_gemm1_deg<<<GB1 + HB, 256, 0, stream>>>(x, W1, TsA, dstp, degi, rank);

    // hierarchical scan (partial) + dinv + BN fold
    k_scan1<<<NB, 256, 0, stream>>>(degi, rp, bsum, dinv);
    k_scan2_bn<<<1, 256, 0, stream>>>(bsum, b1, g1, be1, m1, v1,
                                      b2, g2, be2, m2, v2, sc1, sh1, sc2, sh2);

    // CSR fill (no atomics, u16)
    k_fill<<<FB, 256, 0, stream>>>(srcp, dstp, rp, bsum, rank, eidx);

    // ---- layer 1 aggregate (Ts1 unscaled) ----
    k_agg1<<<NN / 4, 256, 0, stream>>>(TsA, rp, bsum, eidx, dinv, sc1, sh1, actB);

    // ---- layer 2: GEMM (pre-scaled by dinv) + aggregate ----
    k_mfma_gemm128<<<GB1, 256, 0, stream>>>(actB, W2, dinv, TsA);
    k_agg2<<<NN / 4, 256, 0, stream>>>(TsA, rp, bsum, eidx, dinv, sc2, sh2, actB);

    // ---- layer 3: GEMM (pre-scaled) + aggregate + log_softmax ----
    k_mfma_gemm16<<<(NN + 255) / 256, 256, 0, stream>>>(actB, W3, dinv, TcC);
    k_agg16_lsm<<<(NN + 31) / 32, 256, 0, stream>>>(TcC, rp, bsum, eidx, dinv, b3, out);
}